// Round 1
// baseline (2888.407 us; speedup 1.0000x reference)
//
#include <hip/hip_runtime.h>
#include <hip/hip_bf16.h>
#include <stdint.h>

// Problem constants (from reference)
#define N_NODES 100000
#define N_EDGES 1600000
#define D_NODE  32
#define D_EDGE  16
#define D_IN    48   // D_NODE + D_EDGE
#define D_HID   64
#define D_OUT   32

// Workspace layout (bytes)
#define ACC_BYTES ((size_t)N_NODES * D_OUT * 4)          // 12,800,000 fp32 accumulator
#define FLAGS_OFF ACC_BYTES                              // 2 ints: {is_bf16, is_int64}
#define W1T_OFF   (ACC_BYTES + 64)                       // fp32 W1^T [64][48], 16B aligned
#define B1_OFF    (W1T_OFF + (size_t)D_HID * D_IN * 4)
#define W2_OFF    (B1_OFF + (size_t)D_HID * 4)
#define B2_OFF    (W2_OFF + (size_t)D_HID * D_OUT * 4)

__device__ inline float bf2f(unsigned int u16) {
    return __uint_as_float(u16 << 16);
}
__device__ inline unsigned short f2bf_rne(float f) {
    unsigned int x = __float_as_uint(f);
    unsigned int r = (x + 0x7FFFu + ((x >> 16) & 1u)) >> 16;
    return (unsigned short)r;
}
__device__ inline float ld_f(const void* p, int i, int isbf) {
    if (isbf) return bf2f(((const unsigned short*)p)[i]);
    return ((const float*)p)[i];
}

// ---------------------------------------------------------------------------
// Prep: detect dtypes on-device, convert+transpose weights to fp32 in ws.
// fp32 data viewed as bf16: low 16-bit words have random exponent bits ->
// some |v| >= 2^13 among first 64 halfwords with prob ~1-5e-9. bf16 N(0,1)
// data never exceeds exponent 129. int64 viewed as int32: odd words all 0.
// ---------------------------------------------------------------------------
__global__ void prep_kernel(const void* __restrict__ xq, const void* __restrict__ idxq,
                            const void* __restrict__ W1q, const void* __restrict__ b1q,
                            const void* __restrict__ W2q, const void* __restrict__ b2q,
                            char* __restrict__ ws) {
    __shared__ int s_isbf;
    if (threadIdx.x == 0) {
        const unsigned short* u = (const unsigned short*)xq;
        int isbf = 1;
        for (int i = 0; i < 64; ++i) {
            int e = (u[i] >> 7) & 0xFF;
            if (e >= 140) { isbf = 0; break; }
        }
        const int* w = (const int*)idxq;
        int is64 = 1;
        for (int i = 1; i < 64; i += 2) {
            if (w[i] != 0) { is64 = 0; break; }
        }
        int* flags = (int*)(ws + FLAGS_OFF);
        flags[0] = isbf;
        flags[1] = is64;
        s_isbf = isbf;
    }
    __syncthreads();
    const int isbf = s_isbf;
    float* W1t = (float*)(ws + W1T_OFF);
    float* b1  = (float*)(ws + B1_OFF);
    float* W2  = (float*)(ws + W2_OFF);
    float* b2  = (float*)(ws + B2_OFF);
    for (int i = threadIdx.x; i < D_HID * D_IN; i += blockDim.x) {
        int j = i / D_IN, k = i % D_IN;           // W1t[j][k] = W1[k][j]
        W1t[i] = ld_f(W1q, k * D_HID + j, isbf);
    }
    for (int i = threadIdx.x; i < D_HID * D_OUT; i += blockDim.x)
        W2[i] = ld_f(W2q, i, isbf);
    if (threadIdx.x < D_HID) b1[threadIdx.x] = ld_f(b1q, threadIdx.x, isbf);
    if (threadIdx.x < D_OUT) b2[threadIdx.x] = ld_f(b2q, threadIdx.x, isbf);
}

// ---------------------------------------------------------------------------
// Edge MLP + atomic scatter. One thread = one edge. Weights read via
// wave-uniform addresses (j rolled, k/m unrolled) -> scalar cache s_loads,
// FMAs are v_fmac with SGPR operand; h_j fused straight into o[] so neither
// h nor W ever touches LDS/VGPR arrays with dynamic indexing.
// ---------------------------------------------------------------------------
__global__ __launch_bounds__(256) void edge_mlp_kernel(
        const void* __restrict__ xq, const void* __restrict__ idxq,
        const void* __restrict__ eaq,
        const char* __restrict__ wsro, float* __restrict__ acc) {
    __shared__ int s_flags[2];
    if (threadIdx.x < 2)
        s_flags[threadIdx.x] = ((const int*)(wsro + FLAGS_OFF))[threadIdx.x];
    __syncthreads();
    const int isbf = s_flags[0];
    const int is64 = s_flags[1];

    const float* __restrict__ W1t = (const float*)(wsro + W1T_OFF);
    const float* __restrict__ b1  = (const float*)(wsro + B1_OFF);
    const float* __restrict__ W2  = (const float*)(wsro + W2_OFF);
    const float* __restrict__ b2  = (const float*)(wsro + B2_OFF);

    const int e = blockIdx.x * 256 + threadIdx.x;   // grid sized exactly: E % 256 == 0
    int dst, src;
    if (is64) {
        const long long* ip = (const long long*)idxq;
        dst = (int)ip[e];
        src = (int)ip[N_EDGES + e];
    } else {
        const int* ip = (const int*)idxq;
        dst = ip[e];
        src = ip[N_EDGES + e];
    }

    float inp[D_IN];
    if (isbf) {
        const uint4* xp = (const uint4*)((const unsigned short*)xq + (size_t)src * D_NODE);
#pragma unroll
        for (int t = 0; t < 4; ++t) {
            uint4 v = xp[t];
            inp[t*8+0] = __uint_as_float(v.x << 16); inp[t*8+1] = __uint_as_float(v.x & 0xFFFF0000u);
            inp[t*8+2] = __uint_as_float(v.y << 16); inp[t*8+3] = __uint_as_float(v.y & 0xFFFF0000u);
            inp[t*8+4] = __uint_as_float(v.z << 16); inp[t*8+5] = __uint_as_float(v.z & 0xFFFF0000u);
            inp[t*8+6] = __uint_as_float(v.w << 16); inp[t*8+7] = __uint_as_float(v.w & 0xFFFF0000u);
        }
        const uint4* ap = (const uint4*)((const unsigned short*)eaq + (size_t)e * D_EDGE);
#pragma unroll
        for (int t = 0; t < 2; ++t) {
            uint4 v = ap[t];
            inp[32+t*8+0] = __uint_as_float(v.x << 16); inp[32+t*8+1] = __uint_as_float(v.x & 0xFFFF0000u);
            inp[32+t*8+2] = __uint_as_float(v.y << 16); inp[32+t*8+3] = __uint_as_float(v.y & 0xFFFF0000u);
            inp[32+t*8+4] = __uint_as_float(v.z << 16); inp[32+t*8+5] = __uint_as_float(v.z & 0xFFFF0000u);
            inp[32+t*8+6] = __uint_as_float(v.w << 16); inp[32+t*8+7] = __uint_as_float(v.w & 0xFFFF0000u);
        }
    } else {
        const float4* xp = (const float4*)((const float*)xq + (size_t)src * D_NODE);
#pragma unroll
        for (int t = 0; t < 8; ++t) {
            float4 v = xp[t];
            inp[t*4+0] = v.x; inp[t*4+1] = v.y; inp[t*4+2] = v.z; inp[t*4+3] = v.w;
        }
        const float4* ap = (const float4*)((const float*)eaq + (size_t)e * D_EDGE);
#pragma unroll
        for (int t = 0; t < 4; ++t) {
            float4 v = ap[t];
            inp[32+t*4+0] = v.x; inp[32+t*4+1] = v.y; inp[32+t*4+2] = v.z; inp[32+t*4+3] = v.w;
        }
    }

    float o[D_OUT];
#pragma unroll
    for (int m = 0; m < D_OUT; ++m) o[m] = b2[m];

    for (int j = 0; j < D_HID; ++j) {           // rolled: wave-uniform W addresses
        float s = b1[j];
#pragma unroll
        for (int k = 0; k < D_IN; ++k)
            s = fmaf(inp[k], W1t[j * D_IN + k], s);
        s = fmaxf(s, 0.0f);
#pragma unroll
        for (int m = 0; m < D_OUT; ++m)
            o[m] = fmaf(s, W2[j * D_OUT + m], o[m]);
    }

    float* ap = acc + (size_t)dst * D_OUT;
#pragma unroll
    for (int m = 0; m < D_OUT; ++m)
        atomicAdd(ap + m, o[m]);
}

// ---------------------------------------------------------------------------
// Finalize: fp32 accumulator -> output (bf16 RNE or fp32), 8 elems/thread.
// ---------------------------------------------------------------------------
__global__ void finalize_kernel(const float* __restrict__ acc, void* __restrict__ out,
                                const char* __restrict__ wsro) {
    __shared__ int s_isbf;
    if (threadIdx.x == 0) s_isbf = ((const int*)(wsro + FLAGS_OFF))[0];
    __syncthreads();
    const int c = blockIdx.x * blockDim.x + threadIdx.x;     // chunk of 8 floats
    if (c >= (N_NODES * D_OUT) / 8) return;
    const float4* a = (const float4*)acc + (size_t)c * 2;
    float4 v0 = a[0], v1 = a[1];
    if (s_isbf) {
        uint4 p;
        p.x = (unsigned int)f2bf_rne(v0.x) | ((unsigned int)f2bf_rne(v0.y) << 16);
        p.y = (unsigned int)f2bf_rne(v0.z) | ((unsigned int)f2bf_rne(v0.w) << 16);
        p.z = (unsigned int)f2bf_rne(v1.x) | ((unsigned int)f2bf_rne(v1.y) << 16);
        p.w = (unsigned int)f2bf_rne(v1.z) | ((unsigned int)f2bf_rne(v1.w) << 16);
        ((uint4*)out)[c] = p;
    } else {
        float4* op = (float4*)out + (size_t)c * 2;
        op[0] = v0;
        op[1] = v1;
    }
}

extern "C" void kernel_launch(void* const* d_in, const int* in_sizes, int n_in,
                              void* d_out, int out_size, void* d_ws, size_t ws_size,
                              hipStream_t stream) {
    const void* x   = d_in[0];
    const void* idx = d_in[1];
    const void* ea  = d_in[2];
    const void* W1  = d_in[3];
    const void* b1  = d_in[4];
    const void* W2  = d_in[5];
    const void* b2  = d_in[6];
    char* ws = (char*)d_ws;

    // zero the fp32 accumulator (ws is re-poisoned to 0xAA before every call)
    hipMemsetAsync(d_ws, 0, ACC_BYTES, stream);

    hipLaunchKernelGGL(prep_kernel, dim3(1), dim3(256), 0, stream,
                       x, idx, W1, b1, W2, b2, ws);

    hipLaunchKernelGGL(edge_mlp_kernel, dim3(N_EDGES / 256), dim3(256), 0, stream,
                       x, idx, ea, (const char*)ws, (float*)ws);

    const int chunks = (N_NODES * D_OUT) / 8;
    hipLaunchKernelGGL(finalize_kernel, dim3((chunks + 255) / 256), dim3(256), 0, stream,
                       (const float*)ws, d_out, (const char*)ws);
}

// Round 2
// 495.945 us; speedup vs baseline: 5.8241x; 5.8241x over previous
//
#include <hip/hip_runtime.h>
#include <hip/hip_bf16.h>
#include <stdint.h>

// Problem constants (from reference)
#define N_NODES 100000
#define N_EDGES 1600000
#define D_NODE  32
#define D_EDGE  16
#define D_IN    48   // D_NODE + D_EDGE
#define D_HID   64
#define D_OUT   32

// ---------------- OLD (fallback) workspace layout ----------------
#define ACC_BYTES ((size_t)N_NODES * D_OUT * 4)
#define FLAGS_OFF ACC_BYTES
#define W1T_OFF   (ACC_BYTES + 64)
#define B1_OFF    (W1T_OFF + (size_t)D_HID * D_IN * 4)
#define B2OFF_W2  (B1_OFF + (size_t)D_HID * 4)
#define B2_OFF    (B2OFF_W2 + (size_t)D_HID * D_OUT * 4)

// ---------------- NEW (sorted-scatter) workspace layout ----------------
#define NFLAGS_OFF  ((size_t)0)
#define NW1T_OFF    ((size_t)64)
#define NB1_OFF     (NW1T_OFF + (size_t)D_HID * D_IN * 4)     // 12352
#define NW2_OFF     (NB1_OFF + (size_t)D_HID * 4)             // 12608
#define NB2_OFF     (NW2_OFF + (size_t)D_HID * D_OUT * 4)     // 20800
#define COUNTS_OFF  ((size_t)32768)                           // N_NODES ints
#define OFFSETS_OFF ((size_t)458752)                          // N_NODES+1 ints
#define CURSOR_OFF  ((size_t)884736)                          // N_NODES ints
#define BLKSUM_OFF  ((size_t)1310720)                         // 512 ints
#define MSG_OFF     ((size_t)8388608)                         // message rows

#define SCAN_NB 391   // ceil(100000/256)

__device__ inline float bf2f(unsigned int u16) {
    return __uint_as_float(u16 << 16);
}
__device__ inline unsigned short f2bf_rne(float f) {
    unsigned int x = __float_as_uint(f);
    unsigned int r = (x + 0x7FFFu + ((x >> 16) & 1u)) >> 16;
    return (unsigned short)r;
}
__device__ inline float ld_f(const void* p, int i, int isbf) {
    if (isbf) return bf2f(((const unsigned short*)p)[i]);
    return ((const float*)p)[i];
}

// ---------------------------------------------------------------------------
// Prep: detect dtypes on-device, convert+transpose weights to fp32 in ws.
// Offsets passed in so both old and new layouts can use it.
// ---------------------------------------------------------------------------
__global__ void prep_kernel(const void* __restrict__ xq, const void* __restrict__ idxq,
                            const void* __restrict__ W1q, const void* __restrict__ b1q,
                            const void* __restrict__ W2q, const void* __restrict__ b2q,
                            char* __restrict__ ws,
                            size_t flags_off, size_t w1t_off, size_t b1_off,
                            size_t w2_off, size_t b2_off) {
    __shared__ int s_isbf;
    if (threadIdx.x == 0) {
        const unsigned short* u = (const unsigned short*)xq;
        int isbf = 1;
        for (int i = 0; i < 64; ++i) {
            int e = (u[i] >> 7) & 0xFF;
            if (e >= 140) { isbf = 0; break; }
        }
        const int* w = (const int*)idxq;
        int is64 = 1;
        for (int i = 1; i < 64; i += 2) {
            if (w[i] != 0) { is64 = 0; break; }
        }
        int* flags = (int*)(ws + flags_off);
        flags[0] = isbf;
        flags[1] = is64;
        s_isbf = isbf;
    }
    __syncthreads();
    const int isbf = s_isbf;
    float* W1t = (float*)(ws + w1t_off);
    float* b1  = (float*)(ws + b1_off);
    float* W2  = (float*)(ws + w2_off);
    float* b2  = (float*)(ws + b2_off);
    for (int i = threadIdx.x; i < D_HID * D_IN; i += blockDim.x) {
        int j = i / D_IN, k = i % D_IN;           // W1t[j][k] = W1[k][j]
        W1t[i] = ld_f(W1q, k * D_HID + j, isbf);
    }
    for (int i = threadIdx.x; i < D_HID * D_OUT; i += blockDim.x)
        W2[i] = ld_f(W2q, i, isbf);
    if (threadIdx.x < D_HID) b1[threadIdx.x] = ld_f(b1q, threadIdx.x, isbf);
    if (threadIdx.x < D_OUT) b2[threadIdx.x] = ld_f(b2q, threadIdx.x, isbf);
}

// ---------------------------------------------------------------------------
// NEW PATH kernels
// ---------------------------------------------------------------------------
__global__ __launch_bounds__(256) void hist_kernel(const void* __restrict__ idxq,
                                                   char* __restrict__ ws) {
    const int is64 = ((const int*)(ws + NFLAGS_OFF))[1];
    const int e = blockIdx.x * 256 + threadIdx.x;
    int dst;
    if (is64) dst = (int)((const long long*)idxq)[e];
    else      dst = ((const int*)idxq)[e];
    atomicAdd((int*)(ws + COUNTS_OFF) + dst, 1);
}

__global__ __launch_bounds__(256) void scan_block_kernel(char* __restrict__ ws) {
    __shared__ int s[256];
    const int* counts = (const int*)(ws + COUNTS_OFF);
    int* offs   = (int*)(ws + OFFSETS_OFF);
    int* blksum = (int*)(ws + BLKSUM_OFF);
    const int t = threadIdx.x;
    const int i = blockIdx.x * 256 + t;
    int v = (i < N_NODES) ? counts[i] : 0;
    s[t] = v;
    __syncthreads();
    for (int d = 1; d < 256; d <<= 1) {
        int a = (t >= d) ? s[t - d] : 0;
        __syncthreads();
        s[t] += a;
        __syncthreads();
    }
    if (i < N_NODES) offs[i] = s[t] - v;      // local exclusive
    if (t == 255) blksum[blockIdx.x] = s[255];
}

__global__ __launch_bounds__(512) void scan_tops_kernel(char* __restrict__ ws) {
    __shared__ int s[512];
    int* blksum = (int*)(ws + BLKSUM_OFF);
    const int t = threadIdx.x;
    int v = (t < SCAN_NB) ? blksum[t] : 0;
    s[t] = v;
    __syncthreads();
    for (int d = 1; d < 512; d <<= 1) {
        int a = (t >= d) ? s[t - d] : 0;
        __syncthreads();
        s[t] += a;
        __syncthreads();
    }
    if (t < SCAN_NB) blksum[t] = s[t] - v;    // exclusive block offsets
}

__global__ __launch_bounds__(256) void scan_add_kernel(char* __restrict__ ws) {
    int* offs   = (int*)(ws + OFFSETS_OFF);
    int* cursor = (int*)(ws + CURSOR_OFF);
    const int* blksum = (const int*)(ws + BLKSUM_OFF);
    const int i = blockIdx.x * 256 + threadIdx.x;
    if (i < N_NODES) {
        int o = offs[i] + blksum[blockIdx.x];
        offs[i] = o;
        cursor[i] = o;
    }
    if (i == 0) offs[N_NODES] = N_EDGES;
}

// Edge MLP; writes message row at rank-order position (no fp32 atomics).
// mode 0: fp32 rows (128B); mode 1: bf16 rows (64B).
__global__ __launch_bounds__(256) void edge_mlp_msg_kernel(
        const void* __restrict__ xq, const void* __restrict__ idxq,
        const void* __restrict__ eaq,
        const char* __restrict__ wsro,          // flags/weights (read-only region)
        int* __restrict__ cursor,               // CURSOR region
        char* __restrict__ msg,                 // MSG region
        int mode) {
    __shared__ int s_flags[2];
    if (threadIdx.x < 2)
        s_flags[threadIdx.x] = ((const int*)(wsro + NFLAGS_OFF))[threadIdx.x];
    __syncthreads();
    const int isbf = s_flags[0];
    const int is64 = s_flags[1];

    const float* __restrict__ W1t = (const float*)(wsro + NW1T_OFF);
    const float* __restrict__ b1  = (const float*)(wsro + NB1_OFF);
    const float* __restrict__ W2  = (const float*)(wsro + NW2_OFF);
    const float* __restrict__ b2  = (const float*)(wsro + NB2_OFF);

    const int e = blockIdx.x * 256 + threadIdx.x;
    int dst, src;
    if (is64) {
        const long long* ip = (const long long*)idxq;
        dst = (int)ip[e];
        src = (int)ip[N_EDGES + e];
    } else {
        const int* ip = (const int*)idxq;
        dst = ip[e];
        src = ip[N_EDGES + e];
    }

    // issue the rank atomic early; latency hides under the MLP
    const int pos = atomicAdd(cursor + dst, 1);

    float inp[D_IN];
    if (isbf) {
        const uint4* xp = (const uint4*)((const unsigned short*)xq + (size_t)src * D_NODE);
#pragma unroll
        for (int t = 0; t < 4; ++t) {
            uint4 v = xp[t];
            inp[t*8+0] = __uint_as_float(v.x << 16); inp[t*8+1] = __uint_as_float(v.x & 0xFFFF0000u);
            inp[t*8+2] = __uint_as_float(v.y << 16); inp[t*8+3] = __uint_as_float(v.y & 0xFFFF0000u);
            inp[t*8+4] = __uint_as_float(v.z << 16); inp[t*8+5] = __uint_as_float(v.z & 0xFFFF0000u);
            inp[t*8+6] = __uint_as_float(v.w << 16); inp[t*8+7] = __uint_as_float(v.w & 0xFFFF0000u);
        }
        const uint4* ap = (const uint4*)((const unsigned short*)eaq + (size_t)e * D_EDGE);
#pragma unroll
        for (int t = 0; t < 2; ++t) {
            uint4 v = ap[t];
            inp[32+t*8+0] = __uint_as_float(v.x << 16); inp[32+t*8+1] = __uint_as_float(v.x & 0xFFFF0000u);
            inp[32+t*8+2] = __uint_as_float(v.y << 16); inp[32+t*8+3] = __uint_as_float(v.y & 0xFFFF0000u);
            inp[32+t*8+4] = __uint_as_float(v.z << 16); inp[32+t*8+5] = __uint_as_float(v.z & 0xFFFF0000u);
            inp[32+t*8+6] = __uint_as_float(v.w << 16); inp[32+t*8+7] = __uint_as_float(v.w & 0xFFFF0000u);
        }
    } else {
        const float4* xp = (const float4*)((const float*)xq + (size_t)src * D_NODE);
#pragma unroll
        for (int t = 0; t < 8; ++t) {
            float4 v = xp[t];
            inp[t*4+0] = v.x; inp[t*4+1] = v.y; inp[t*4+2] = v.z; inp[t*4+3] = v.w;
        }
        const float4* ap = (const float4*)((const float*)eaq + (size_t)e * D_EDGE);
#pragma unroll
        for (int t = 0; t < 4; ++t) {
            float4 v = ap[t];
            inp[32+t*4+0] = v.x; inp[32+t*4+1] = v.y; inp[32+t*4+2] = v.z; inp[32+t*4+3] = v.w;
        }
    }

    float o[D_OUT];
#pragma unroll
    for (int m = 0; m < D_OUT; ++m) o[m] = b2[m];

    for (int j = 0; j < D_HID; ++j) {           // rolled: wave-uniform W addresses
        float s = b1[j];
#pragma unroll
        for (int k = 0; k < D_IN; ++k)
            s = fmaf(inp[k], W1t[j * D_IN + k], s);
        s = fmaxf(s, 0.0f);
#pragma unroll
        for (int m = 0; m < D_OUT; ++m)
            o[m] = fmaf(s, W2[j * D_OUT + m], o[m]);
    }

    if (mode == 0) {
        float4* row = (float4*)(msg + (size_t)pos * 128);
#pragma unroll
        for (int t = 0; t < 8; ++t) {
            float4 v;
            v.x = o[t*4+0]; v.y = o[t*4+1]; v.z = o[t*4+2]; v.w = o[t*4+3];
            row[t] = v;
        }
    } else {
        uint4* row = (uint4*)(msg + (size_t)pos * 64);
#pragma unroll
        for (int t = 0; t < 4; ++t) {
            uint4 p;
            p.x = (unsigned int)f2bf_rne(o[t*8+0]) | ((unsigned int)f2bf_rne(o[t*8+1]) << 16);
            p.y = (unsigned int)f2bf_rne(o[t*8+2]) | ((unsigned int)f2bf_rne(o[t*8+3]) << 16);
            p.z = (unsigned int)f2bf_rne(o[t*8+4]) | ((unsigned int)f2bf_rne(o[t*8+5]) << 16);
            p.w = (unsigned int)f2bf_rne(o[t*8+6]) | ((unsigned int)f2bf_rne(o[t*8+7]) << 16);
            row[t] = p;
        }
    }
}

// Node-parallel reduce: half-wave (32 lanes) per node, lane m sums component m
// over the node's contiguous message rows. Fully coalesced 128B/64B line reads.
__global__ __launch_bounds__(256) void reduce_kernel(
        const char* __restrict__ wsro, const char* __restrict__ msg,
        void* __restrict__ out, int mode) {
    const int isbf = ((const int*)(wsro + NFLAGS_OFF))[0];
    const int* offs = (const int*)(wsro + OFFSETS_OFF);
    const int node = (blockIdx.x * 256 + threadIdx.x) >> 5;
    const int m = threadIdx.x & 31;
    if (node >= N_NODES) return;
    const int lo = offs[node], hi = offs[node + 1];
    float s = 0.0f;
    if (mode == 0) {
        const float* p = (const float*)msg + (size_t)lo * 32 + m;
        int k = lo;
        for (; k + 1 < hi; k += 2) {            // 2x unroll: two independent loads
            float a = p[0], b = p[32];
            s += a + b;
            p += 64;
        }
        if (k < hi) s += p[0];
    } else {
        const unsigned short* p = (const unsigned short*)msg + (size_t)lo * 32 + m;
        int k = lo;
        for (; k + 1 < hi; k += 2) {
            float a = bf2f(p[0]), b = bf2f(p[32]);
            s += a + b;
            p += 64;
        }
        if (k < hi) s += bf2f(p[0]);
    }
    if (isbf) ((unsigned short*)out)[(size_t)node * 32 + m] = f2bf_rne(s);
    else      ((float*)out)[(size_t)node * 32 + m] = s;
}

// ---------------------------------------------------------------------------
// OLD PATH (fallback if ws too small): atomic scatter + finalize (Round-1 code)
// ---------------------------------------------------------------------------
__global__ __launch_bounds__(256) void edge_mlp_kernel(
        const void* __restrict__ xq, const void* __restrict__ idxq,
        const void* __restrict__ eaq,
        const char* __restrict__ wsro, float* __restrict__ acc) {
    __shared__ int s_flags[2];
    if (threadIdx.x < 2)
        s_flags[threadIdx.x] = ((const int*)(wsro + FLAGS_OFF))[threadIdx.x];
    __syncthreads();
    const int isbf = s_flags[0];
    const int is64 = s_flags[1];

    const float* __restrict__ W1t = (const float*)(wsro + W1T_OFF);
    const float* __restrict__ b1  = (const float*)(wsro + B1_OFF);
    const float* __restrict__ W2  = (const float*)(wsro + B2OFF_W2);
    const float* __restrict__ b2  = (const float*)(wsro + B2_OFF);

    const int e = blockIdx.x * 256 + threadIdx.x;
    int dst, src;
    if (is64) {
        const long long* ip = (const long long*)idxq;
        dst = (int)ip[e];
        src = (int)ip[N_EDGES + e];
    } else {
        const int* ip = (const int*)idxq;
        dst = ip[e];
        src = ip[N_EDGES + e];
    }

    float inp[D_IN];
    if (isbf) {
        const uint4* xp = (const uint4*)((const unsigned short*)xq + (size_t)src * D_NODE);
#pragma unroll
        for (int t = 0; t < 4; ++t) {
            uint4 v = xp[t];
            inp[t*8+0] = __uint_as_float(v.x << 16); inp[t*8+1] = __uint_as_float(v.x & 0xFFFF0000u);
            inp[t*8+2] = __uint_as_float(v.y << 16); inp[t*8+3] = __uint_as_float(v.y & 0xFFFF0000u);
            inp[t*8+4] = __uint_as_float(v.z << 16); inp[t*8+5] = __uint_as_float(v.z & 0xFFFF0000u);
            inp[t*8+6] = __uint_as_float(v.w << 16); inp[t*8+7] = __uint_as_float(v.w & 0xFFFF0000u);
        }
        const uint4* ap = (const uint4*)((const unsigned short*)eaq + (size_t)e * D_EDGE);
#pragma unroll
        for (int t = 0; t < 2; ++t) {
            uint4 v = ap[t];
            inp[32+t*8+0] = __uint_as_float(v.x << 16); inp[32+t*8+1] = __uint_as_float(v.x & 0xFFFF0000u);
            inp[32+t*8+2] = __uint_as_float(v.y << 16); inp[32+t*8+3] = __uint_as_float(v.y & 0xFFFF0000u);
            inp[32+t*8+4] = __uint_as_float(v.z << 16); inp[32+t*8+5] = __uint_as_float(v.z & 0xFFFF0000u);
            inp[32+t*8+6] = __uint_as_float(v.w << 16); inp[32+t*8+7] = __uint_as_float(v.w & 0xFFFF0000u);
        }
    } else {
        const float4* xp = (const float4*)((const float*)xq + (size_t)src * D_NODE);
#pragma unroll
        for (int t = 0; t < 8; ++t) {
            float4 v = xp[t];
            inp[t*4+0] = v.x; inp[t*4+1] = v.y; inp[t*4+2] = v.z; inp[t*4+3] = v.w;
        }
        const float4* ap = (const float4*)((const float*)eaq + (size_t)e * D_EDGE);
#pragma unroll
        for (int t = 0; t < 4; ++t) {
            float4 v = ap[t];
            inp[32+t*4+0] = v.x; inp[32+t*4+1] = v.y; inp[32+t*4+2] = v.z; inp[32+t*4+3] = v.w;
        }
    }

    float o[D_OUT];
#pragma unroll
    for (int m = 0; m < D_OUT; ++m) o[m] = b2[m];

    for (int j = 0; j < D_HID; ++j) {
        float s = b1[j];
#pragma unroll
        for (int k = 0; k < D_IN; ++k)
            s = fmaf(inp[k], W1t[j * D_IN + k], s);
        s = fmaxf(s, 0.0f);
#pragma unroll
        for (int m = 0; m < D_OUT; ++m)
            o[m] = fmaf(s, W2[j * D_OUT + m], o[m]);
    }

    float* ap = acc + (size_t)dst * D_OUT;
#pragma unroll
    for (int m = 0; m < D_OUT; ++m)
        atomicAdd(ap + m, o[m]);
}

__global__ void finalize_kernel(const float* __restrict__ acc, void* __restrict__ out,
                                const char* __restrict__ wsro) {
    __shared__ int s_isbf;
    if (threadIdx.x == 0) s_isbf = ((const int*)(wsro + FLAGS_OFF))[0];
    __syncthreads();
    const int c = blockIdx.x * blockDim.x + threadIdx.x;
    if (c >= (N_NODES * D_OUT) / 8) return;
    const float4* a = (const float4*)acc + (size_t)c * 2;
    float4 v0 = a[0], v1 = a[1];
    if (s_isbf) {
        uint4 p;
        p.x = (unsigned int)f2bf_rne(v0.x) | ((unsigned int)f2bf_rne(v0.y) << 16);
        p.y = (unsigned int)f2bf_rne(v0.z) | ((unsigned int)f2bf_rne(v0.w) << 16);
        p.z = (unsigned int)f2bf_rne(v1.x) | ((unsigned int)f2bf_rne(v1.y) << 16);
        p.w = (unsigned int)f2bf_rne(v1.z) | ((unsigned int)f2bf_rne(v1.w) << 16);
        ((uint4*)out)[c] = p;
    } else {
        float4* op = (float4*)out + (size_t)c * 2;
        op[0] = v0;
        op[1] = v1;
    }
}

extern "C" void kernel_launch(void* const* d_in, const int* in_sizes, int n_in,
                              void* d_out, int out_size, void* d_ws, size_t ws_size,
                              hipStream_t stream) {
    const void* x   = d_in[0];
    const void* idx = d_in[1];
    const void* ea  = d_in[2];
    const void* W1  = d_in[3];
    const void* b1  = d_in[4];
    const void* W2  = d_in[5];
    const void* b2  = d_in[6];
    char* ws = (char*)d_ws;

    const size_t need_f32 = MSG_OFF + (size_t)N_EDGES * 128;   // ~213.2 MB
    const size_t need_b16 = MSG_OFF + (size_t)N_EDGES * 64;    // ~110.8 MB

    int mode;
    if (ws_size >= need_f32)      mode = 0;
    else if (ws_size >= need_b16) mode = 1;
    else                          mode = -1;   // fallback: Round-1 atomic path

    if (mode < 0) {
        hipMemsetAsync(d_ws, 0, ACC_BYTES, stream);
        hipLaunchKernelGGL(prep_kernel, dim3(1), dim3(256), 0, stream,
                           x, idx, W1, b1, W2, b2, ws,
                           FLAGS_OFF, W1T_OFF, B1_OFF, B2OFF_W2, B2_OFF);
        hipLaunchKernelGGL(edge_mlp_kernel, dim3(N_EDGES / 256), dim3(256), 0, stream,
                           x, idx, ea, (const char*)ws, (float*)ws);
        const int chunks = (N_NODES * D_OUT) / 8;
        hipLaunchKernelGGL(finalize_kernel, dim3((chunks + 255) / 256), dim3(256), 0, stream,
                           (const float*)ws, d_out, (const char*)ws);
        return;
    }

    // zero histogram counters only
    hipMemsetAsync(ws + COUNTS_OFF, 0, (size_t)N_NODES * 4, stream);

    hipLaunchKernelGGL(prep_kernel, dim3(1), dim3(256), 0, stream,
                       x, idx, W1, b1, W2, b2, ws,
                       NFLAGS_OFF, NW1T_OFF, NB1_OFF, NW2_OFF, NB2_OFF);

    hipLaunchKernelGGL(hist_kernel, dim3(N_EDGES / 256), dim3(256), 0, stream, idx, ws);

    hipLaunchKernelGGL(scan_block_kernel, dim3(SCAN_NB), dim3(256), 0, stream, ws);
    hipLaunchKernelGGL(scan_tops_kernel,  dim3(1),       dim3(512), 0, stream, ws);
    hipLaunchKernelGGL(scan_add_kernel,   dim3(SCAN_NB), dim3(256), 0, stream, ws);

    hipLaunchKernelGGL(edge_mlp_msg_kernel, dim3(N_EDGES / 256), dim3(256), 0, stream,
                       x, idx, ea, (const char*)ws,
                       (int*)(ws + CURSOR_OFF), ws + MSG_OFF, mode);

    hipLaunchKernelGGL(reduce_kernel, dim3((N_NODES * 32 + 255) / 256), dim3(256), 0, stream,
                       (const char*)ws, (const char*)(ws + MSG_OFF), d_out, mode);
}